// Round 4
// baseline (943.405 us; speedup 1.0000x reference)
//
#include <hip/hip_runtime.h>
#include <hip/hip_fp16.h>

typedef _Float16 half8  __attribute__((ext_vector_type(8)));
typedef _Float16 half2v __attribute__((ext_vector_type(2)));
typedef float    f32x4  __attribute__((ext_vector_type(4)));

#define MFMA16(af, bf, cf) __builtin_amdgcn_mfma_f32_16x16x32_f16((af), (bf), (cf), 0, 0, 0)

// ---------------- workspace layout (halves) ----------------
#define WS_WL1  0                         // layer1 [k1;rk1] packed: [nt0..31][kt0..7][lane][8] = 131072
#define WS_RK0  131072                    // rk0 packed: [nt0..31][kt0..3][lane][8] = 65536
#define WS_W0   (131072 + 65536)          // W0' = W_in@k0 packed: [nt0..31][kt0..2][lane][8] = 49152
#define WS_WOUT (WS_W0 + 49152)           // W_out packed: [nt0..1][kt0..3][lane][8] = 4096
#define WS_B0   (WS_WOUT + 4096)          // float b0'[512] (as float*, 2 halves each)

// ---------------- LDS layout (halves) ----------------
#define PA0 104                            // 96 cols (x|acc) + 8 pad
#define PH  136                            // 128 cols + 8 pad
#define L_A0   0                           // 2 x [16][104] = 3328
#define L_H0   3328                        // 2 x [16][136] = 4352
#define L_H1   (L_H0 + 4352)               // 7680: 2 x [16][136]
#define L_WOUT (L_H1 + 4352)               // 12032: [2nt][4kt][512] = 4096
#define L_K1   (L_WOUT + 4096)             // 16128: k1 kt0..3: [nt][kt][512] = 65536
#define L_TOT  (L_K1 + 65536)              // 81664 halves = 163328 B

__device__ __forceinline__ float sigm(float x) {
    return __builtin_amdgcn_rcpf(1.0f + __builtin_amdgcn_exp2f(-1.442695041f * x));
}
__device__ __forceinline__ float tanh_(float x) {
    return 1.0f - 2.0f * __builtin_amdgcn_rcpf(__builtin_amdgcn_exp2f(2.885390082f * x) + 1.0f);
}
// raw barrier: drain LDS only; global loads/stores stay in flight.
__device__ __forceinline__ void bar() {
    asm volatile("s_waitcnt lgkmcnt(0)" ::: "memory");
    __builtin_amdgcn_s_barrier();
    asm volatile("" ::: "memory");
}

// ---- pack kernels (identical layouts to R3) ----
__global__ void pack_layer_k(const float* __restrict__ kk, const float* __restrict__ rk,
                             _Float16* __restrict__ dst)
{
    int idx  = blockIdx.x * 256 + threadIdx.x;
    int j    = idx & 7;
    int lane = (idx >> 3) & 63;
    int fk   = idx >> 9;
    int kt   = fk & 7;
    int nt   = fk >> 3;
    int w = nt >> 3, ln = nt & 7, g = ln >> 1, hh = ln & 1;
    int col = g*128 + w*32 + hh*16 + (lane & 15);
    int row = kt*32 + (lane >> 4)*8 + j;
    float v = (row < 128) ? kk[row*512 + col] : rk[(row - 128)*512 + col];
    dst[idx] = (_Float16)v;
}

__global__ void pack_rk(const float* __restrict__ rk, _Float16* __restrict__ dst)
{
    int idx = blockIdx.x * 256 + threadIdx.x;
    int j = idx & 7, lane = (idx >> 3) & 63, fk = idx >> 9;
    int kt = fk & 3, nt = fk >> 2;
    int w = nt >> 3, ln = nt & 7, g = ln >> 1, hh = ln & 1;
    int col = g*128 + w*32 + hh*16 + (lane & 15);
    int row = kt*32 + (lane >> 4)*8 + j;
    dst[idx] = (_Float16)rk[row*512 + col];
}

__global__ void pack_w0(const float* __restrict__ W_in, const float* __restrict__ k0,
                        _Float16* __restrict__ dst)
{
    int idx = blockIdx.x * 256 + threadIdx.x;
    int j = idx & 7, lane = (idx >> 3) & 63, fk = idx >> 9;
    int kt = fk % 3, nt = fk / 3;
    int w = nt >> 3, ln = nt & 7, g = ln >> 1, hh = ln & 1;
    int col = g*128 + w*32 + hh*16 + (lane & 15);
    int row = kt*32 + (lane >> 4)*8 + j;
    float s = 0.f;
    #pragma unroll 4
    for (int k = 0; k < 128; ++k) s += W_in[row*128 + k] * k0[k*512 + col];
    dst[idx] = (_Float16)s;
}

__global__ void pack_b0(const float* __restrict__ b_in, const float* __restrict__ k0,
                        const float* __restrict__ bb0, float* __restrict__ b0p)
{
    int col = blockIdx.x * 256 + threadIdx.x;
    float s = bb0[col];
    #pragma unroll 4
    for (int k = 0; k < 128; ++k) s += b_in[k] * k0[k*512 + col];
    b0p[col] = s;
}

__global__ void pack_wout(const float* __restrict__ W_out, _Float16* __restrict__ dst)
{
    int idx = blockIdx.x * 256 + threadIdx.x;
    int j = idx & 7, lane = (idx >> 3) & 63, fk = idx >> 9;
    int kt = fk & 3, nt = fk >> 2;
    int col = nt*16 + (lane & 15);
    int row = kt*32 + (lane >> 4)*8 + j;
    dst[idx] = (_Float16)W_out[row*32 + col];
}

__global__ __launch_bounds__(512, 2)
void acclstm_main(const float* __restrict__ xin,
                  const _Float16* __restrict__ wl1p, const _Float16* __restrict__ rk0p,
                  const _Float16* __restrict__ w0p,  const _Float16* __restrict__ woutp,
                  const float* __restrict__ b0p, const float* __restrict__ bb1,
                  const float* __restrict__ bout, float* __restrict__ out)
{
    __shared__ __align__(16) _Float16 lds[L_TOT];
    const int tid  = threadIdx.x;
    const int W    = tid >> 6;
    const int lane = tid & 63;
    const int w4   = W & 3;
    const int hh   = W >> 2;
    const int l15  = lane & 15;
    const int lg   = lane >> 4;
    const int b0   = blockIdx.x << 4;
    const int colw = w4*32 + hh*16 + l15;

    // ---- LDS fills ----
    for (int i = tid; i < 8192; i += 512) {
        int h = i << 3, nt = h >> 11, rem = h & 2047;
        *reinterpret_cast<uint4*>(&lds[L_K1 + h]) =
            *reinterpret_cast<const uint4*>(&wl1p[nt*4096 + rem]);
    }
    *reinterpret_cast<uint4*>(&lds[L_WOUT + (tid << 3)]) =
        *reinterpret_cast<const uint4*>(&woutp[tid << 3]);
    {
        uint4 z; z.x = z.y = z.z = z.w = 0u;
        for (int i = tid; i < 1504; i += 512)
            *reinterpret_cast<uint4*>(&lds[i << 3]) = z;
    }

    // ---- persistent weight fragments ----
    half8 w0r[4][3], rk0r[4][4], rk1r[4][4];
    #pragma unroll
    for (int g = 0; g < 4; ++g) {
        const int nt = w4*8 + g*2 + hh;
        #pragma unroll
        for (int kt = 0; kt < 3; ++kt)
            w0r[g][kt] = *reinterpret_cast<const half8*>(&w0p[(nt*3 + kt)*512 + lane*8]);
        #pragma unroll
        for (int kt = 0; kt < 4; ++kt)
            rk0r[g][kt] = *reinterpret_cast<const half8*>(&rk0p[(nt*4 + kt)*512 + lane*8]);
        #pragma unroll
        for (int kt = 0; kt < 4; ++kt)
            rk1r[g][kt] = *reinterpret_cast<const half8*>(&wl1p[(nt*8 + 4 + kt)*512 + lane*8]);
    }
    float b0v[4], b1v[4];
    #pragma unroll
    for (int g = 0; g < 4; ++g) {
        b0v[g] = b0p[g*128 + colw];
        b1v[g] = bb1[g*128 + colw];
    }
    const float boutv = (W < 2) ? bout[W*16 + l15] : 0.0f;

    f32x4 c0 = {0.f,0.f,0.f,0.f}, c1 = {0.f,0.f,0.f,0.f}, accv = {0.f,0.f,0.f,0.f};

    const int xrow = tid >> 5, xc2 = (tid & 31) << 1;
    __syncthreads();
    float2 xr = *reinterpret_cast<const float2*>(&xin[(size_t)(b0 + xrow)*16384 + xc2]);
    {
        half2v xh = { (_Float16)xr.x, (_Float16)xr.y };
        *reinterpret_cast<half2v*>(&lds[L_A0 + xrow*PA0 + xc2]) = xh;
    }
    xr = *reinterpret_cast<const float2*>(&xin[(size_t)(b0 + xrow)*16384 + 64 + xc2]);
    __syncthreads();

    // prefetched h0-prev fragments for the upcoming seg1 (parity 0 buffers = zeros)
    half8 pfh0[4];
    #pragma unroll
    for (int kt = 0; kt < 4; ++kt)
        pfh0[kt] = *reinterpret_cast<const half8*>(&lds[L_H0 + l15*PH + kt*32 + lg*8]);

    auto step = [&](auto PARc, int t) {
        constexpr int PAR = decltype(PARc)::value;
        constexpr int A0r = L_A0 + PAR*1664,       A0w = L_A0 + (PAR^1)*1664;
        constexpr int H0r = L_H0 + PAR*2176,       H0w = L_H0 + (PAR^1)*2176;
        constexpr int H1r = L_H1 + PAR*2176,       H1w = L_H1 + (PAR^1)*2176;
        (void)H0r;

        // ================= seg1: z0 = [x|acc]@W0' + h0_prev@rk0 =================
        {
            // only 3 LDS reads here; h0-prev frags are prefetched registers
            half8 ax0 = *reinterpret_cast<const half8*>(&lds[A0r + l15*PA0 +  0 + lg*8]);
            half8 ax1 = *reinterpret_cast<const half8*>(&lds[A0r + l15*PA0 + 32 + lg*8]);
            half8 aac = *reinterpret_cast<const half8*>(&lds[A0r + l15*PA0 + 64 + lg*8]);

            f32x4 z0 = {b0v[0],b0v[0],b0v[0],b0v[0]};
            f32x4 z1 = {b0v[1],b0v[1],b0v[1],b0v[1]};
            f32x4 z2 = {b0v[2],b0v[2],b0v[2],b0v[2]};
            #pragma unroll
            for (int kt = 0; kt < 4; ++kt) {          // register-fed: starts immediately
                z0 = MFMA16(pfh0[kt], rk0r[0][kt], z0);
                z1 = MFMA16(pfh0[kt], rk0r[1][kt], z1);
                z2 = MFMA16(pfh0[kt], rk0r[2][kt], z2);
            }
            z0 = MFMA16(ax0, w0r[0][0], z0); z1 = MFMA16(ax0, w0r[1][0], z1); z2 = MFMA16(ax0, w0r[2][0], z2);
            z0 = MFMA16(ax1, w0r[0][1], z0); z1 = MFMA16(ax1, w0r[1][1], z1); z2 = MFMA16(ax1, w0r[2][1], z2);
            z0 = MFMA16(aac, w0r[0][2], z0); z1 = MFMA16(aac, w0r[1][2], z1); z2 = MFMA16(aac, w0r[2][2], z2);

            // gate-o chain (MFMA pipe) weaves with i/f/g nonlin (trans pipe)
            f32x4 z3 = {b0v[3],b0v[3],b0v[3],b0v[3]};
            #pragma unroll
            for (int kt = 0; kt < 4; ++kt) z3 = MFMA16(pfh0[kt], rk0r[3][kt], z3);
            z3 = MFMA16(ax0, w0r[3][0], z3);
            z3 = MFMA16(ax1, w0r[3][1], z3);
            z3 = MFMA16(aac, w0r[3][2], z3);

            #pragma unroll
            for (int r = 0; r < 4; ++r) {
                float iv = sigm (z0[r]);
                float fv = sigm (z1[r]);
                float gv = tanh_(z2[r]);
                c0[r] = fv * c0[r] + iv * gv;
            }
            #pragma unroll
            for (int r = 0; r < 4; ++r) {
                float ov = sigm(z3[r]);
                lds[H0w + (lg*4 + r)*PH + colw] = (_Float16)(ov * tanh_(c0[r]));
            }
        }
        bar();  // barA: h0 ready

        // ================= seg2: z1 = h0@k1(LDS) + h1_prev@rk1 =================
        {
            half8 ah1[4], ah0[4];
            #pragma unroll
            for (int kt = 0; kt < 4; ++kt)
                ah1[kt] = *reinterpret_cast<const half8*>(&lds[H1r + l15*PH + kt*32 + lg*8]);
            #pragma unroll
            for (int kt = 0; kt < 4; ++kt)
                ah0[kt] = *reinterpret_cast<const half8*>(&lds[H0w + l15*PH + kt*32 + lg*8]);

            f32x4 z0 = {b1v[0],b1v[0],b1v[0],b1v[0]};
            f32x4 z1 = {b1v[1],b1v[1],b1v[1],b1v[1]};
            f32x4 z2 = {b1v[2],b1v[2],b1v[2],b1v[2]};
            #pragma unroll
            for (int kt = 0; kt < 4; ++kt) {          // reg-weight MFMAs run while LDS drains
                z0 = MFMA16(ah1[kt], rk1r[0][kt], z0);
                z1 = MFMA16(ah1[kt], rk1r[1][kt], z1);
                z2 = MFMA16(ah1[kt], rk1r[2][kt], z2);
            }
            #pragma unroll
            for (int kt = 0; kt < 4; ++kt) {          // k1 frags for gates 0..2, rolling
                half8 kf0 = *reinterpret_cast<const half8*>(&lds[L_K1 + ((w4*8 + 0 + hh)*4 + kt)*512 + lane*8]);
                half8 kf1 = *reinterpret_cast<const half8*>(&lds[L_K1 + ((w4*8 + 2 + hh)*4 + kt)*512 + lane*8]);
                half8 kf2 = *reinterpret_cast<const half8*>(&lds[L_K1 + ((w4*8 + 4 + hh)*4 + kt)*512 + lane*8]);
                z0 = MFMA16(ah0[kt], kf0, z0);
                z1 = MFMA16(ah0[kt], kf1, z1);
                z2 = MFMA16(ah0[kt], kf2, z2);
            }

            // gate-o chain (rk1 + k1-g3 reads) weaves with i/f/g nonlin
            f32x4 z3 = {b1v[3],b1v[3],b1v[3],b1v[3]};
            #pragma unroll
            for (int kt = 0; kt < 4; ++kt) z3 = MFMA16(ah1[kt], rk1r[3][kt], z3);
            #pragma unroll
            for (int kt = 0; kt < 4; ++kt) {
                half8 kf3 = *reinterpret_cast<const half8*>(&lds[L_K1 + ((w4*8 + 6 + hh)*4 + kt)*512 + lane*8]);
                z3 = MFMA16(ah0[kt], kf3, z3);
            }

            #pragma unroll
            for (int r = 0; r < 4; ++r) {
                float iv = sigm (z0[r]);
                float fv = sigm (z1[r]);
                float gv = tanh_(z2[r]);
                c1[r] = fv * c1[r] + iv * gv;
            }
            #pragma unroll
            for (int r = 0; r < 4; ++r) {
                float ov = sigm(z3[r]);
                lds[H1w + (lg*4 + r)*PH + colw] = (_Float16)(ov * tanh_(c1[r]));
            }
        }
        bar();  // barB: h1 ready

        // ================= tail: prefetch + GEMM4 + staging =================
        // prefetch next seg1's h0-prev frags (H0w published by barA this step)
        #pragma unroll
        for (int kt = 0; kt < 4; ++kt)
            pfh0[kt] = *reinterpret_cast<const half8*>(&lds[H0w + l15*PH + kt*32 + lg*8]);

        if (W < 2) {
            f32x4 rr = {boutv,boutv,boutv,boutv};
            #pragma unroll
            for (int kt = 0; kt < 4; ++kt) {
                half8 af = *reinterpret_cast<const half8*>(&lds[H1w + l15*PH + kt*32 + lg*8]);
                half8 wf = *reinterpret_cast<const half8*>(&lds[L_WOUT + (W*4 + kt)*512 + lane*8]);
                rr = MFMA16(af, wf, rr);
            }
            #pragma unroll
            for (int r = 0; r < 4; ++r) {
                float res = rr[r];
                out[(size_t)(b0 + lg*4 + r)*8192 + t*32 + W*16 + l15] = res;
                accv[r] += res;
                lds[A0w + (lg*4 + r)*PA0 + 64 + W*16 + l15] = (_Float16)accv[r];
            }
        }
        {
            half2v xh = { (_Float16)xr.x, (_Float16)xr.y };
            *reinterpret_cast<half2v*>(&lds[A0w + xrow*PA0 + xc2]) = xh;
            int tn = t + 2; if (tn > 255) tn = 255;
            xr = *reinterpret_cast<const float2*>(&xin[(size_t)(b0 + xrow)*16384 + tn*64 + xc2]);
        }
        bar();  // barC: A0_next (x|acc) ready
    };

    #pragma unroll 1
    for (int t = 0; t < 256; t += 2) {
        step(std::integral_constant<int,0>{}, t);
        step(std::integral_constant<int,1>{}, t + 1);
    }
}

extern "C" void kernel_launch(void* const* d_in, const int* in_sizes, int n_in,
                              void* d_out, int out_size, void* d_ws, size_t ws_size,
                              hipStream_t stream) {
    (void)in_sizes; (void)n_in; (void)out_size; (void)ws_size;
    const float* x     = (const float*)d_in[0];
    const float* W_in  = (const float*)d_in[1];
    const float* b_in  = (const float*)d_in[2];
    const float* k0    = (const float*)d_in[3];
    const float* rk0   = (const float*)d_in[4];
    const float* bb0   = (const float*)d_in[5];
    const float* k1    = (const float*)d_in[6];
    const float* rk1   = (const float*)d_in[7];
    const float* bb1   = (const float*)d_in[8];
    const float* W_out = (const float*)d_in[9];
    const float* b_out = (const float*)d_in[10];
    float* out = (float*)d_out;

    _Float16* ws    = (_Float16*)d_ws;
    _Float16* wl1p  = ws + WS_WL1;
    _Float16* rk0p  = ws + WS_RK0;
    _Float16* w0p   = ws + WS_W0;
    _Float16* woutp = ws + WS_WOUT;
    float*    b0p   = (float*)(ws + WS_B0);

    pack_layer_k<<<512, 256, 0, stream>>>(k1, rk1, wl1p);
    pack_rk     <<<256, 256, 0, stream>>>(rk0, rk0p);
    pack_w0     <<<192, 256, 0, stream>>>(W_in, k0, w0p);
    pack_b0     <<<2,   256, 0, stream>>>(b_in, k0, bb0, b0p);
    pack_wout   <<<16,  256, 0, stream>>>(W_out, woutp);
    acclstm_main<<<256, 512, 0, stream>>>(x, wl1p, rk0p, w0p, woutp,
                                          b0p, bb1, b_out, out);
}